// Round 5
// baseline (3113.366 us; speedup 1.0000x reference)
//
#include <hip/hip_runtime.h>

typedef _Float16 half8 __attribute__((ext_vector_type(8)));
typedef _Float16 half4 __attribute__((ext_vector_type(4)));
typedef float floatx4 __attribute__((ext_vector_type(4)));

static constexpr int BATCH = 1024;
static constexpr int NIN   = 512;    // in_features
static constexpr int MOUT  = 1024;   // out_features
static constexpr float LAMBD = 0.2f;
static constexpr float TOLF  = 1e-4f;
static constexpr int MAX_ITERS = 100;
static constexpr int MM = BATCH * MOUT;   // 1M elements

// Fragment-swizzled layout for MFMA operands (A: rows, B: cols), f16:
//   flat = ((tile16*32 + kchunk32)*64 + lane)*8 + elem
//   lane = (idx&15) | (((k>>3)&3)<<4), elem = k&7
// so a wave loads one 16(x)x32(k) fragment as a single coalesced 16B/lane load.
__device__ __forceinline__ size_t swz(int idx, int k) {
    return ((((size_t)(idx >> 4) * 32 + (k >> 5)) * 64 +
             ((idx & 15) | (((k >> 3) & 3) << 4))) << 3) + (k & 7);
}

// ---------------------------------------------------------------------------
// zero-init: v, u, enc, dec, solved
// ---------------------------------------------------------------------------
__global__ __launch_bounds__(256) void zero_init(float* v, float* u, float* enc,
                                                 float* dec, int* solved) {
    int i = blockIdx.x * 256 + threadIdx.x;
    if (i < MM) { v[i] = 0.f; u[i] = 0.f; enc[i] = 0.f; }
    if (i < MM / 2) dec[i] = 0.f;
    if (i < BATCH) solved[i] = 0;
}

// ---------------------------------------------------------------------------
// Th/Tl = B-fragment-swizzled split-f16 of Minv (B operand: col=n, kdim=k).
// ---------------------------------------------------------------------------
__global__ __launch_bounds__(256) void split_minv(const float* __restrict__ Minv,
                                                  _Float16* __restrict__ Th,
                                                  _Float16* __restrict__ Tl) {
    int g = blockIdx.x * 256 + threadIdx.x;   // 131072 threads
    int n = g & 1023, k0 = (g >> 10) << 3;
    half8 h, l;
    #pragma unroll
    for (int e = 0; e < 8; ++e) {
        float val = Minv[(size_t)(k0 + e) * MOUT + n];
        _Float16 hh = (_Float16)val;
        h[e] = hh;
        l[e] = (_Float16)(val - (float)hh);
    }
    size_t off = swz(n, k0);
    *(half8*)&Th[off] = h;
    *(half8*)&Tl[off] = l;
}

// ---------------------------------------------------------------------------
// adb = x @ w^T (fp32, once). Epilogue emits beff = adb as A-swizzled h/l.
// ---------------------------------------------------------------------------
__global__ __launch_bounds__(256) void gemm_adb(const float* __restrict__ x,
                                                const float* __restrict__ w,
                                                float* __restrict__ adb,
                                                _Float16* __restrict__ bh,
                                                _Float16* __restrict__ bl) {
    __shared__ float As[16][68];
    __shared__ float Bs[16][68];
    const int tid = threadIdx.x;
    const int i0 = (blockIdx.x >> 4) * 64, j0 = (blockIdx.x & 15) * 64;
    const int tx = tid & 15, ty = tid >> 4;
    const int lr = tid >> 2, lk = (tid & 3) << 2;
    float acc[4][4] = {};
    for (int k0 = 0; k0 < NIN; k0 += 16) {
        float4 a4 = *(const float4*)&x[(i0 + lr) * NIN + k0 + lk];
        As[lk + 0][lr] = a4.x; As[lk + 1][lr] = a4.y;
        As[lk + 2][lr] = a4.z; As[lk + 3][lr] = a4.w;
        float4 b4 = *(const float4*)&w[(j0 + lr) * NIN + k0 + lk];
        Bs[lk + 0][lr] = b4.x; Bs[lk + 1][lr] = b4.y;
        Bs[lk + 2][lr] = b4.z; Bs[lk + 3][lr] = b4.w;
        __syncthreads();
        #pragma unroll
        for (int kk = 0; kk < 16; ++kk) {
            float4 a_ = *(const float4*)&As[kk][ty << 2];
            float4 b_ = *(const float4*)&Bs[kk][tx << 2];
            #pragma unroll
            for (int r = 0; r < 4; ++r) {
                float av = r == 0 ? a_.x : r == 1 ? a_.y : r == 2 ? a_.z : a_.w;
                acc[r][0] = fmaf(av, b_.x, acc[r][0]);
                acc[r][1] = fmaf(av, b_.y, acc[r][1]);
                acc[r][2] = fmaf(av, b_.z, acc[r][2]);
                acc[r][3] = fmaf(av, b_.w, acc[r][3]);
            }
        }
        __syncthreads();
    }
    const int k4 = j0 + (tx << 2);
    #pragma unroll
    for (int r = 0; r < 4; ++r) {
        const int row = i0 + (ty << 2) + r;
        *(float4*)&adb[(size_t)row * MOUT + k4] =
            make_float4(acc[r][0], acc[r][1], acc[r][2], acc[r][3]);
        half4 h, l;
        #pragma unroll
        for (int e = 0; e < 4; ++e) {
            _Float16 hh = (_Float16)acc[r][e];
            h[e] = hh;
            l[e] = (_Float16)(acc[r][e] - (float)hh);
        }
        size_t off = swz(row, k4);
        *(half4*)&bh[off] = h;
        *(half4*)&bl[off] = l;
    }
}

// ---------------------------------------------------------------------------
// Iteration GEMM, LDS-free: all fragments via coalesced global loads from
// pre-swizzled arrays. 128x128 block tile, 4 waves of 64x64 (4x4 MFMA tiles),
// 3-product split-f16, split-K (grid = 64*S blocks).
// ---------------------------------------------------------------------------
__global__ __launch_bounds__(256, 1)
void gemm_xk(const _Float16* __restrict__ bh, const _Float16* __restrict__ bl,
             const _Float16* __restrict__ Th, const _Float16* __restrict__ Tl,
             float* __restrict__ xkp, const int* __restrict__ solved,
             int steps) {
    const int bid = blockIdx.x;
    const int c = bid >> 6, t = bid & 63;
    const int mt = t >> 3, nt = t & 7;
    const int m0 = mt << 7, n0 = nt << 7;
    const int tid = threadIdx.x, lane = tid & 63;

    bool done = ((volatile const int*)solved)[m0 + lane] &&
                ((volatile const int*)solved)[m0 + 64 + lane];
    if (__ballot(done) == ~0ull) return;   // whole 128-row stripe solved

    const int wm = (tid >> 7) & 1, wn = (tid >> 6) & 1;
    const int rt0 = (mt << 3) + (wm << 2);   // first of 4 A row-tiles
    const int ct0 = (nt << 3) + (wn << 2);   // first of 4 B col-tiles
    const int kc0 = c * steps;

    // base pointers at (tile, kc0, lane): tile stride 16384 halves, k-chunk 512
    const _Float16* pAh = bh + ((((size_t)rt0 * 32 + kc0) * 64 + lane) << 3);
    const _Float16* pAl = bl + ((((size_t)rt0 * 32 + kc0) * 64 + lane) << 3);
    const _Float16* pBh = Th + ((((size_t)ct0 * 32 + kc0) * 64 + lane) << 3);
    const _Float16* pBl = Tl + ((((size_t)ct0 * 32 + kc0) * 64 + lane) << 3);

    floatx4 acc[4][4] = {};
    #pragma unroll 2
    for (int s = 0; s < steps; ++s) {
        half8 ah[4], al[4], bhf[4], blf[4];
        #pragma unroll
        for (int i = 0; i < 4; ++i) {
            ah[i]  = *(const half8*)(pAh + (size_t)i * 16384 + (size_t)s * 512);
            al[i]  = *(const half8*)(pAl + (size_t)i * 16384 + (size_t)s * 512);
            bhf[i] = *(const half8*)(pBh + (size_t)i * 16384 + (size_t)s * 512);
            blf[i] = *(const half8*)(pBl + (size_t)i * 16384 + (size_t)s * 512);
        }
        #pragma unroll
        for (int i = 0; i < 4; ++i)
            #pragma unroll
            for (int j = 0; j < 4; ++j) {
                acc[i][j] = __builtin_amdgcn_mfma_f32_16x16x32_f16(
                    ah[i], blf[j], acc[i][j], 0, 0, 0);
                acc[i][j] = __builtin_amdgcn_mfma_f32_16x16x32_f16(
                    al[i], bhf[j], acc[i][j], 0, 0, 0);
                acc[i][j] = __builtin_amdgcn_mfma_f32_16x16x32_f16(
                    ah[i], bhf[j], acc[i][j], 0, 0, 0);
            }
    }

    // C/D layout: col = lane&15, row = (lane>>4)*4 + reg  [m89 verified]
    float* op = xkp + (size_t)c * MM;
    const int orow = (lane >> 4) << 2;
    #pragma unroll
    for (int i = 0; i < 4; ++i) {
        const int gr = m0 + (wm << 6) + (i << 4) + orow;
        #pragma unroll
        for (int j = 0; j < 4; ++j) {
            const int gc = n0 + (wn << 6) + (j << 4) + (lane & 15);
            #pragma unroll
            for (int r = 0; r < 4; ++r)
                op[(size_t)(gr + r) * MOUT + gc] = acc[i][j][r];
        }
    }
}

// ---------------------------------------------------------------------------
// Row update: 1 wave per row (256 blocks x 4 waves), shuffle-only reduction.
// Sums split-K partials, softshrink, norms, convergence, freeze; emits
// beff h/l in A-swizzled layout for the next gemm_xk.
// ---------------------------------------------------------------------------
__global__ __launch_bounds__(256) void update(const float* __restrict__ adb,
                                              const float* __restrict__ xkp,
                                              float* __restrict__ v,
                                              float* __restrict__ u,
                                              _Float16* __restrict__ bh,
                                              _Float16* __restrict__ bl,
                                              float* __restrict__ enc,
                                              int* solved, int S) {
    const int tid = threadIdx.x, lane = tid & 63;
    const int row = (blockIdx.x << 2) + (tid >> 6);
    if (((volatile const int*)solved)[row]) return;   // wave-uniform

    float vn[16];
    float dx2 = 0.f, x2 = 0.f;
    #pragma unroll
    for (int cch = 0; cch < 4; ++cch) {
        const int k4 = (cch << 8) + (lane << 2);
        const size_t j = ((size_t)row << 10) + k4;
        float4 kx = *(const float4*)&xkp[j];
        for (int cc = 1; cc < S; ++cc) {
            float4 p = *(const float4*)&xkp[(size_t)cc * MM + j];
            kx.x += p.x; kx.y += p.y; kx.z += p.z; kx.w += p.w;
        }
        float4 uu = *(const float4*)&u[j];
        float4 vv = *(const float4*)&v[j];
        float4 aa = *(const float4*)&adb[j];
        float kxa[4] = {kx.x, kx.y, kx.z, kx.w};
        float uua[4] = {uu.x, uu.y, uu.z, uu.w};
        float vva[4] = {vv.x, vv.y, vv.z, vv.w};
        float aaa[4] = {aa.x, aa.y, aa.z, aa.w};
        float vne[4], une[4];
        half4 h, l;
        #pragma unroll
        for (int e = 0; e < 4; ++e) {
            float tt = kxa[e] + uua[e];
            float av = fabsf(tt) - LAMBD;
            float vv_ = av > 0.f ? copysignf(av, tt) : 0.f;
            vne[e] = vv_;
            une[e] = uua[e] + kxa[e] - vv_;
            float d = vv_ - vva[e];
            dx2 += d * d;
            x2 += vv_ * vv_;
            vn[(cch << 2) + e] = vv_;
            float nb = aaa[e] + vv_ - une[e];
            _Float16 hh = (_Float16)nb;
            h[e] = hh;
            l[e] = (_Float16)(nb - (float)hh);
        }
        *(float4*)&v[j] = make_float4(vne[0], vne[1], vne[2], vne[3]);
        *(float4*)&u[j] = make_float4(une[0], une[1], une[2], une[3]);
        size_t off = swz(row, k4);
        *(half4*)&bh[off] = h;
        *(half4*)&bl[off] = l;
    }
    #pragma unroll
    for (int off = 32; off; off >>= 1) {
        dx2 += __shfl_xor(dx2, off);
        x2  += __shfl_xor(x2, off);
    }
    if (dx2 < TOLF * TOLF * x2) {   // x2==0 -> false (NaN semantics)
        #pragma unroll
        for (int cch = 0; cch < 4; ++cch) {
            const size_t j = ((size_t)row << 10) + (cch << 8) + (lane << 2);
            *(float4*)&enc[j] = make_float4(vn[(cch << 2) + 0], vn[(cch << 2) + 1],
                                            vn[(cch << 2) + 2], vn[(cch << 2) + 3]);
        }
        if (lane == 0) ((volatile int*)solved)[row] = 1;
    }
}

// ---------------------------------------------------------------------------
// dec = enc @ w (fp32, once). Split-K=2 via atomicAdd (exact: 2 addends
// commute bitwise in fp32). dec zeroed in zero_init.
// ---------------------------------------------------------------------------
__global__ __launch_bounds__(256) void gemm_dec(const float* __restrict__ enc,
                                                const float* __restrict__ w,
                                                float* __restrict__ dec) {
    __shared__ float As[16][68];
    __shared__ float Bs[16][68];
    const int tid = threadIdx.x;
    const int bid = blockIdx.x;
    const int c = bid >> 7, t = bid & 127;
    const int i0 = (t >> 3) << 6, j0 = (t & 7) << 6;
    const int kb = c << 9;
    const int tx = tid & 15, ty = tid >> 4;
    const int la_r = tid >> 2, la_k = (tid & 3) << 2;
    const int lb_k = tid >> 4, lb_j = (tid & 15) << 2;
    float acc[4][4] = {};
    for (int k0 = kb; k0 < kb + 512; k0 += 16) {
        float4 a4 = *(const float4*)&enc[(i0 + la_r) * MOUT + k0 + la_k];
        As[la_k + 0][la_r] = a4.x; As[la_k + 1][la_r] = a4.y;
        As[la_k + 2][la_r] = a4.z; As[la_k + 3][la_r] = a4.w;
        float4 b4 = *(const float4*)&w[(k0 + lb_k) * NIN + j0 + lb_j];
        *(float4*)&Bs[lb_k][lb_j] = b4;
        __syncthreads();
        #pragma unroll
        for (int kk = 0; kk < 16; ++kk) {
            float4 a_ = *(const float4*)&As[kk][ty << 2];
            float4 b_ = *(const float4*)&Bs[kk][tx << 2];
            #pragma unroll
            for (int r = 0; r < 4; ++r) {
                float av = r == 0 ? a_.x : r == 1 ? a_.y : r == 2 ? a_.z : a_.w;
                acc[r][0] = fmaf(av, b_.x, acc[r][0]);
                acc[r][1] = fmaf(av, b_.y, acc[r][1]);
                acc[r][2] = fmaf(av, b_.z, acc[r][2]);
                acc[r][3] = fmaf(av, b_.w, acc[r][3]);
            }
        }
        __syncthreads();
    }
    #pragma unroll
    for (int r = 0; r < 4; ++r) {
        const size_t idx = (size_t)(i0 + (ty << 2) + r) * NIN + j0 + (tx << 2);
        #pragma unroll
        for (int e = 0; e < 4; ++e) atomicAdd(&dec[idx + e], acc[r][e]);
    }
}

// ---------------------------------------------------------------------------
extern "C" void kernel_launch(void* const* d_in, const int* in_sizes, int n_in,
                              void* d_out, int out_size, void* d_ws, size_t ws_size,
                              hipStream_t stream) {
    const float* x    = (const float*)d_in[0];
    const float* w    = (const float*)d_in[1];
    const float* Minv = (const float*)d_in[2];

    float* enc = (float*)d_out;          // encoded: 1024*1024
    float* dec = enc + MM;               // decoded: 1024*512

    // ws (floats): adb MM | v MM | u MM | xkp S*MM | bh/bl/Th/Tl MM halves each
    float* ws  = (float*)d_ws;
    float* adb = ws;
    float* v   = ws + (size_t)MM;
    float* u   = ws + 2 * (size_t)MM;
    float* xkp = ws + 3 * (size_t)MM;

    int S = 1;
    if (ws_size >= (size_t)MM * 36 + 4096) S = 4;
    else if (ws_size >= (size_t)MM * 28 + 4096) S = 2;
    const int steps = 32 / S;

    _Float16* bh = (_Float16*)(xkp + (size_t)S * MM);
    _Float16* bl = bh + (size_t)MM;
    _Float16* Th = bl + (size_t)MM;
    _Float16* Tl = Th + (size_t)MM;
    int* solved  = (int*)(Tl + (size_t)MM);

    zero_init<<<(MM + 255) / 256, 256, 0, stream>>>(v, u, enc, dec, solved);
    split_minv<<<512, 256, 0, stream>>>(Minv, Th, Tl);
    gemm_adb<<<256, 256, 0, stream>>>(x, w, adb, bh, bl);

    for (int it = 0; it < MAX_ITERS; ++it) {
        gemm_xk<<<64 * S, 256, 0, stream>>>(bh, bl, Th, Tl, xkp, solved, steps);
        update<<<256, 256, 0, stream>>>(adb, xkp, v, u, bh, bl, enc, solved, S);
    }

    gemm_dec<<<256, 256, 0, stream>>>(enc, w, dec);
}

// Round 6
// 2455.741 us; speedup vs baseline: 1.2678x; 1.2678x over previous
//
#include <hip/hip_runtime.h>

typedef _Float16 half8 __attribute__((ext_vector_type(8)));
typedef _Float16 half4 __attribute__((ext_vector_type(4)));
typedef float floatx4 __attribute__((ext_vector_type(4)));

static constexpr int BATCH = 1024;
static constexpr int NIN   = 512;    // in_features
static constexpr int MOUT  = 1024;   // out_features
static constexpr float LAMBD = 0.2f;
static constexpr float TOLF  = 1e-4f;
static constexpr int MAX_ITERS = 100;
static constexpr int MM = BATCH * MOUT;   // 1M elements

// Fragment-swizzled layout for 16x16x32 MFMA operands (A: rows, B: cols), f16:
//   flat = ((tile16*32 + kchunk32)*64 + lane)*8 + elem
//   lane = (idx&15) | (((k>>3)&3)<<4), elem = k&7
// A wave loads one 16(x)x32(k) fragment as one coalesced 16B/lane load.
__device__ __forceinline__ size_t swz(int idx, int k) {
    return ((((size_t)(idx >> 4) * 32 + (k >> 5)) * 64 +
             ((idx & 15) | (((k >> 3) & 3) << 4))) << 3) + (k & 7);
}

// ---------------------------------------------------------------------------
__global__ __launch_bounds__(256) void zero_init(float* v, float* u, float* enc,
                                                 float* dec, int* solved) {
    int i = blockIdx.x * 256 + threadIdx.x;
    if (i < MM) { v[i] = 0.f; u[i] = 0.f; enc[i] = 0.f; }
    if (i < MM / 2) dec[i] = 0.f;
    if (i < BATCH) solved[i] = 0;
}

// ---------------------------------------------------------------------------
// Th/Tl = B-fragment-swizzled split-f16 of Minv (B operand: col=n, kdim=k).
// ---------------------------------------------------------------------------
__global__ __launch_bounds__(256) void split_minv(const float* __restrict__ Minv,
                                                  _Float16* __restrict__ Th,
                                                  _Float16* __restrict__ Tl) {
    int g = blockIdx.x * 256 + threadIdx.x;   // 131072 threads
    int n = g & 1023, k0 = (g >> 10) << 3;
    half8 h, l;
    #pragma unroll
    for (int e = 0; e < 8; ++e) {
        float val = Minv[(size_t)(k0 + e) * MOUT + n];
        _Float16 hh = (_Float16)val;
        h[e] = hh;
        l[e] = (_Float16)(val - (float)hh);
    }
    size_t off = swz(n, k0);
    *(half8*)&Th[off] = h;
    *(half8*)&Tl[off] = l;
}

// ---------------------------------------------------------------------------
// adb = x @ w^T (fp32, once). Epilogue emits beff = adb as A-swizzled h/l.
// ---------------------------------------------------------------------------
__global__ __launch_bounds__(256) void gemm_adb(const float* __restrict__ x,
                                                const float* __restrict__ w,
                                                float* __restrict__ adb,
                                                _Float16* __restrict__ bh,
                                                _Float16* __restrict__ bl) {
    __shared__ float As[16][68];
    __shared__ float Bs[16][68];
    const int tid = threadIdx.x;
    const int i0 = (blockIdx.x >> 4) * 64, j0 = (blockIdx.x & 15) * 64;
    const int tx = tid & 15, ty = tid >> 4;
    const int lr = tid >> 2, lk = (tid & 3) << 2;
    float acc[4][4] = {};
    for (int k0 = 0; k0 < NIN; k0 += 16) {
        float4 a4 = *(const float4*)&x[(i0 + lr) * NIN + k0 + lk];
        As[lk + 0][lr] = a4.x; As[lk + 1][lr] = a4.y;
        As[lk + 2][lr] = a4.z; As[lk + 3][lr] = a4.w;
        float4 b4 = *(const float4*)&w[(j0 + lr) * NIN + k0 + lk];
        Bs[lk + 0][lr] = b4.x; Bs[lk + 1][lr] = b4.y;
        Bs[lk + 2][lr] = b4.z; Bs[lk + 3][lr] = b4.w;
        __syncthreads();
        #pragma unroll
        for (int kk = 0; kk < 16; ++kk) {
            float4 a_ = *(const float4*)&As[kk][ty << 2];
            float4 b_ = *(const float4*)&Bs[kk][tx << 2];
            #pragma unroll
            for (int r = 0; r < 4; ++r) {
                float av = r == 0 ? a_.x : r == 1 ? a_.y : r == 2 ? a_.z : a_.w;
                acc[r][0] = fmaf(av, b_.x, acc[r][0]);
                acc[r][1] = fmaf(av, b_.y, acc[r][1]);
                acc[r][2] = fmaf(av, b_.z, acc[r][2]);
                acc[r][3] = fmaf(av, b_.w, acc[r][3]);
            }
        }
        __syncthreads();
    }
    const int k4 = j0 + (tx << 2);
    #pragma unroll
    for (int r = 0; r < 4; ++r) {
        const int row = i0 + (ty << 2) + r;
        *(float4*)&adb[(size_t)row * MOUT + k4] =
            make_float4(acc[r][0], acc[r][1], acc[r][2], acc[r][3]);
        half4 h, l;
        #pragma unroll
        for (int e = 0; e < 4; ++e) {
            _Float16 hh = (_Float16)acc[r][e];
            h[e] = hh;
            l[e] = (_Float16)(acc[r][e] - (float)hh);
        }
        size_t off = swz(row, k4);
        *(half4*)&bh[off] = h;
        *(half4*)&bl[off] = l;
    }
}

// ---------------------------------------------------------------------------
// Iteration GEMM: 128x128 block tile, 4 waves of 64x64 (4x4 of 16x16x32).
// A (bh/bl) staged to LDS via global_load_lds (flat swizzled copy, double-
// buffered, conflict-free b128 reads). B (Th/Tl) direct global->reg,
// prefetched one step. Split-K: c = bid & cmask (XCD-local K partition).
// ---------------------------------------------------------------------------
__global__ __launch_bounds__(256, 1)
void gemm_xk(const _Float16* __restrict__ bh, const _Float16* __restrict__ bl,
             const _Float16* __restrict__ Th, const _Float16* __restrict__ Tl,
             float* __restrict__ xkp, const int* __restrict__ solved,
             int steps, int cmask, int cshift) {
    const int bid = blockIdx.x;
    const int c = bid & cmask, t = bid >> cshift;
    const int mt = t >> 3, nt = t & 7;
    const int m0 = mt << 7, n0 = nt << 7;
    const int tid = threadIdx.x, lane = tid & 63;

    bool done = ((volatile const int*)solved)[m0 + lane] &&
                ((volatile const int*)solved)[m0 + 64 + lane];
    if (__ballot(done) == ~0ull) return;   // whole 128-row stripe solved

    __shared__ _Float16 Ash[2][16 * 512];  // [buf][frag 0..15][512 halves]

    const int wv = tid >> 6;
    const int wm = wv >> 1, wn = wv & 1;
    const int kf0 = c * steps;             // first k32-frag index
    const int ct0 = (nt << 3) + (wn << 2); // first of 4 B col-tiles

    // B fragment base: ((ct0*32 + kf0)*64 + lane)*8
    const _Float16* pTh = Th + ((((size_t)ct0 * 32 + kf0) * 64 + lane) << 3);
    const _Float16* pTl = Tl + ((((size_t)ct0 * 32 + kf0) * 64 + lane) << 3);

    // stage frags f = wv*4+i (f = rt*2 + hl) of step s into Ash[buf]
    auto stage = [&](int buf, int s) {
        #pragma unroll
        for (int i = 0; i < 4; ++i) {
            const int f = (wv << 2) + i;
            const int rt = f >> 1;
            const _Float16* src = ((f & 1) ? bl : bh) +
                ((((size_t)((mt << 3) + rt) * 32 + kf0 + s) << 9) + (lane << 3));
            __builtin_amdgcn_global_load_lds(
                (const __attribute__((address_space(1))) void*)src,
                (__attribute__((address_space(3))) void*)&Ash[buf][f << 9],
                16, 0, 0);
        }
    };

    floatx4 acc[4][4] = {};
    half8 cbh[4], cbl[4], nbh[4], nbl[4];
    #pragma unroll
    for (int j = 0; j < 4; ++j) {          // B frags for s=0
        cbh[j] = *(const half8*)(pTh + ((size_t)j << 14));
        cbl[j] = *(const half8*)(pTl + ((size_t)j << 14));
    }
    stage(0, 0);

    for (int s = 0; s < steps; ++s) {
        const int buf = s & 1;
        __syncthreads();                   // stage(s) complete (vmcnt drain)
        if (s + 1 < steps) {
            stage(buf ^ 1, s + 1);
            #pragma unroll
            for (int j = 0; j < 4; ++j) {  // prefetch B for s+1
                nbh[j] = *(const half8*)(pTh + ((size_t)j << 14) + ((size_t)(s + 1) << 9));
                nbl[j] = *(const half8*)(pTl + ((size_t)j << 14) + ((size_t)(s + 1) << 9));
            }
        }
        half8 ah[4], al[4];
        #pragma unroll
        for (int i = 0; i < 4; ++i) {      // A frags: row-tiles wm*4+i, h & l
            const int f = ((wm << 2) + i) << 1;
            ah[i] = *(const half8*)&Ash[buf][(f << 9) + (lane << 3)];
            al[i] = *(const half8*)&Ash[buf][((f + 1) << 9) + (lane << 3)];
        }
        #pragma unroll
        for (int i = 0; i < 4; ++i)
            #pragma unroll
            for (int j = 0; j < 4; ++j) {
                acc[i][j] = __builtin_amdgcn_mfma_f32_16x16x32_f16(
                    ah[i], cbl[j], acc[i][j], 0, 0, 0);
                acc[i][j] = __builtin_amdgcn_mfma_f32_16x16x32_f16(
                    al[i], cbh[j], acc[i][j], 0, 0, 0);
                acc[i][j] = __builtin_amdgcn_mfma_f32_16x16x32_f16(
                    ah[i], cbh[j], acc[i][j], 0, 0, 0);
            }
        #pragma unroll
        for (int j = 0; j < 4; ++j) { cbh[j] = nbh[j]; cbl[j] = nbl[j]; }
    }

    // C/D layout: col = lane&15, row = (lane>>4)*4 + reg  [m89 verified]
    float* op = xkp + (size_t)c * MM;
    const int orow = (lane >> 4) << 2;
    #pragma unroll
    for (int i = 0; i < 4; ++i) {
        const int gr = m0 + (wm << 6) + (i << 4) + orow;
        #pragma unroll
        for (int j = 0; j < 4; ++j) {
            const int gc = n0 + (wn << 6) + (j << 4) + (lane & 15);
            #pragma unroll
            for (int r = 0; r < 4; ++r)
                op[(size_t)(gr + r) * MOUT + gc] = acc[i][j][r];
        }
    }
}

// ---------------------------------------------------------------------------
// Row update: 1 wave per row (256 blocks x 4 waves), shuffle-only reduction.
// Sums split-K partials, softshrink, norms, convergence, freeze; emits
// beff h/l in A-swizzled layout for the next gemm_xk.
// ---------------------------------------------------------------------------
__global__ __launch_bounds__(256) void update(const float* __restrict__ adb,
                                              const float* __restrict__ xkp,
                                              float* __restrict__ v,
                                              float* __restrict__ u,
                                              _Float16* __restrict__ bh,
                                              _Float16* __restrict__ bl,
                                              float* __restrict__ enc,
                                              int* solved, int S) {
    const int tid = threadIdx.x, lane = tid & 63;
    const int row = (blockIdx.x << 2) + (tid >> 6);
    if (((volatile const int*)solved)[row]) return;   // wave-uniform

    float vn[16];
    float dx2 = 0.f, x2 = 0.f;
    #pragma unroll
    for (int cch = 0; cch < 4; ++cch) {
        const int k4 = (cch << 8) + (lane << 2);
        const size_t j = ((size_t)row << 10) + k4;
        float4 kx = *(const float4*)&xkp[j];
        for (int cc = 1; cc < S; ++cc) {
            float4 p = *(const float4*)&xkp[(size_t)cc * MM + j];
            kx.x += p.x; kx.y += p.y; kx.z += p.z; kx.w += p.w;
        }
        float4 uu = *(const float4*)&u[j];
        float4 vv = *(const float4*)&v[j];
        float4 aa = *(const float4*)&adb[j];
        float kxa[4] = {kx.x, kx.y, kx.z, kx.w};
        float uua[4] = {uu.x, uu.y, uu.z, uu.w};
        float vva[4] = {vv.x, vv.y, vv.z, vv.w};
        float aaa[4] = {aa.x, aa.y, aa.z, aa.w};
        float vne[4], une[4];
        half4 h, l;
        #pragma unroll
        for (int e = 0; e < 4; ++e) {
            float tt = kxa[e] + uua[e];
            float av = fabsf(tt) - LAMBD;
            float vv_ = av > 0.f ? copysignf(av, tt) : 0.f;
            vne[e] = vv_;
            une[e] = uua[e] + kxa[e] - vv_;
            float d = vv_ - vva[e];
            dx2 += d * d;
            x2 += vv_ * vv_;
            vn[(cch << 2) + e] = vv_;
            float nb = aaa[e] + vv_ - une[e];
            _Float16 hh = (_Float16)nb;
            h[e] = hh;
            l[e] = (_Float16)(nb - (float)hh);
        }
        *(float4*)&v[j] = make_float4(vne[0], vne[1], vne[2], vne[3]);
        *(float4*)&u[j] = make_float4(une[0], une[1], une[2], une[3]);
        size_t off = swz(row, k4);
        *(half4*)&bh[off] = h;
        *(half4*)&bl[off] = l;
    }
    #pragma unroll
    for (int off = 32; off; off >>= 1) {
        dx2 += __shfl_xor(dx2, off);
        x2  += __shfl_xor(x2, off);
    }
    if (dx2 < TOLF * TOLF * x2) {   // x2==0 -> false (NaN semantics)
        #pragma unroll
        for (int cch = 0; cch < 4; ++cch) {
            const size_t j = ((size_t)row << 10) + (cch << 8) + (lane << 2);
            *(float4*)&enc[j] = make_float4(vn[(cch << 2) + 0], vn[(cch << 2) + 1],
                                            vn[(cch << 2) + 2], vn[(cch << 2) + 3]);
        }
        if (lane == 0) ((volatile int*)solved)[row] = 1;
    }
}

// ---------------------------------------------------------------------------
// dec = enc @ w (fp32, once). Split-K=2 via atomicAdd (exact for 2 addends).
// ---------------------------------------------------------------------------
__global__ __launch_bounds__(256) void gemm_dec(const float* __restrict__ enc,
                                                const float* __restrict__ w,
                                                float* __restrict__ dec) {
    __shared__ float As[16][68];
    __shared__ float Bs[16][68];
    const int tid = threadIdx.x;
    const int bid = blockIdx.x;
    const int c = bid >> 7, t = bid & 127;
    const int i0 = (t >> 3) << 6, j0 = (t & 7) << 6;
    const int kb = c << 9;
    const int tx = tid & 15, ty = tid >> 4;
    const int la_r = tid >> 2, la_k = (tid & 3) << 2;
    const int lb_k = tid >> 4, lb_j = (tid & 15) << 2;
    float acc[4][4] = {};
    for (int k0 = kb; k0 < kb + 512; k0 += 16) {
        float4 a4 = *(const float4*)&enc[(i0 + la_r) * MOUT + k0 + la_k];
        As[la_k + 0][la_r] = a4.x; As[la_k + 1][la_r] = a4.y;
        As[la_k + 2][la_r] = a4.z; As[la_k + 3][la_r] = a4.w;
        float4 b4 = *(const float4*)&w[(k0 + lb_k) * NIN + j0 + lb_j];
        *(float4*)&Bs[lb_k][lb_j] = b4;
        __syncthreads();
        #pragma unroll
        for (int kk = 0; kk < 16; ++kk) {
            float4 a_ = *(const float4*)&As[kk][ty << 2];
            float4 b_ = *(const float4*)&Bs[kk][tx << 2];
            #pragma unroll
            for (int r = 0; r < 4; ++r) {
                float av = r == 0 ? a_.x : r == 1 ? a_.y : r == 2 ? a_.z : a_.w;
                acc[r][0] = fmaf(av, b_.x, acc[r][0]);
                acc[r][1] = fmaf(av, b_.y, acc[r][1]);
                acc[r][2] = fmaf(av, b_.z, acc[r][2]);
                acc[r][3] = fmaf(av, b_.w, acc[r][3]);
            }
        }
        __syncthreads();
    }
    #pragma unroll
    for (int r = 0; r < 4; ++r) {
        const size_t idx = (size_t)(i0 + (ty << 2) + r) * NIN + j0 + (tx << 2);
        #pragma unroll
        for (int e = 0; e < 4; ++e) atomicAdd(&dec[idx + e], acc[r][e]);
    }
}

// ---------------------------------------------------------------------------
extern "C" void kernel_launch(void* const* d_in, const int* in_sizes, int n_in,
                              void* d_out, int out_size, void* d_ws, size_t ws_size,
                              hipStream_t stream) {
    const float* x    = (const float*)d_in[0];
    const float* w    = (const float*)d_in[1];
    const float* Minv = (const float*)d_in[2];

    float* enc = (float*)d_out;          // encoded: 1024*1024
    float* dec = enc + MM;               // decoded: 1024*512

    // ws (floats): adb MM | v MM | u MM | xkp S*MM | bh/bl/Th/Tl MM halves each
    float* ws  = (float*)d_ws;
    float* adb = ws;
    float* v   = ws + (size_t)MM;
    float* u   = ws + 2 * (size_t)MM;
    float* xkp = ws + 3 * (size_t)MM;

    int S = 2, cshift = 1;
    if (ws_size >= (size_t)MM * 36 + 4096) { S = 4; cshift = 2; }
    const int steps = 32 / S;            // k32-frags per partition

    _Float16* bh = (_Float16*)(xkp + (size_t)S * MM);
    _Float16* bl = bh + (size_t)MM;
    _Float16* Th = bl + (size_t)MM;
    _Float16* Tl = Th + (size_t)MM;
    int* solved  = (int*)(Tl + (size_t)MM);

    zero_init<<<(MM + 255) / 256, 256, 0, stream>>>(v, u, enc, dec, solved);
    split_minv<<<512, 256, 0, stream>>>(Minv, Th, Tl);
    gemm_adb<<<256, 256, 0, stream>>>(x, w, adb, bh, bl);

    for (int it = 0; it < MAX_ITERS; ++it) {
        gemm_xk<<<64 * S, 256, 0, stream>>>(bh, bl, Th, Tl, xkp, solved,
                                            steps, S - 1, cshift);
        update<<<256, 256, 0, stream>>>(adb, xkp, v, u, bh, bl, enc, solved, S);
    }

    gemm_dec<<<256, 256, 0, stream>>>(enc, w, dec);
}